// Round 1
// baseline (485.098 us; speedup 1.0000x reference)
//
#include <hip/hip_runtime.h>
#include <stdint.h>

#define K_DIM 4096
#define N_DIM 4096
#define KB    32          // K / 128
#define QMAXF 127.0f

typedef int v4i __attribute__((ext_vector_type(4)));

__device__ __forceinline__ void async_copy16(void* lds, const void* gptr) {
    __builtin_amdgcn_global_load_lds(
        (__attribute__((address_space(1))) void*)gptr,
        (__attribute__((address_space(3))) void*)lds, 16, 0, 0);
}

// ---------------- activation quant: per (row, 128-block) ----------------
// one block per row m; 256 threads; 4 passes of 1024 elements (8 groups/pass)
__global__ __launch_bounds__(256) void act_quant_kernel(
    const float* __restrict__ x, int8_t* __restrict__ xq,
    float* __restrict__ xs_t, int M)
{
    const int m = blockIdx.x;
    const int t = threadIdx.x;
    const float* xrow = x + (size_t)m * K_DIM;
    int8_t* qrow = xq + (size_t)m * K_DIM;

#pragma unroll
    for (int p = 0; p < 4; ++p) {
        const int base = p * 1024 + t * 4;
        float4 v = *(const float4*)(xrow + base);
        float a = fmaxf(fmaxf(fabsf(v.x), fabsf(v.y)), fmaxf(fabsf(v.z), fabsf(v.w)));
        // amax over the 32 consecutive lanes covering one 128-elem group
#pragma unroll
        for (int off = 1; off < 32; off <<= 1)
            a = fmaxf(a, __shfl_xor(a, off, 64));
        const float s = fmaxf(a / QMAXF, 1e-12f);
        // division (not reciprocal) + rintf to match jnp round-half-even
        float q0 = fminf(fmaxf(rintf(v.x / s), -128.f), 127.f);
        float q1 = fminf(fmaxf(rintf(v.y / s), -128.f), 127.f);
        float q2 = fminf(fmaxf(rintf(v.z / s), -128.f), 127.f);
        float q3 = fminf(fmaxf(rintf(v.w / s), -128.f), 127.f);
        char4 pk;
        pk.x = (char)(int)q0; pk.y = (char)(int)q1;
        pk.z = (char)(int)q2; pk.w = (char)(int)q3;
        *(char4*)(qrow + base) = pk;
        if ((t & 31) == 0) {
            const int g = base >> 7;                 // group index in [0,32)
            xs_t[(size_t)g * M + m] = s;             // transposed [kb][M]
        }
    }
}

// ---------------- weight quant: per 128x128 block ----------------
// one block per (nb,kb); 256 threads; 64 elems/thread kept in registers
__global__ __launch_bounds__(256) void weight_quant_kernel(
    const float* __restrict__ w, int8_t* __restrict__ wq, float* __restrict__ ws)
{
    const int nb = blockIdx.x >> 5;   // / KB
    const int kb = blockIdx.x & 31;
    const int t  = threadIdx.x;
    const int n0 = nb * 128, k0 = kb * 128;

    float4 vals[16];
    float a = 0.f;
#pragma unroll
    for (int ii = 0; ii < 16; ++ii) {
        const int e = ii * 1024 + t * 4;
        const int row = e >> 7, col = e & 127;
        float4 v = *(const float4*)(w + (size_t)(n0 + row) * K_DIM + k0 + col);
        vals[ii] = v;
        a = fmaxf(a, fmaxf(fmaxf(fabsf(v.x), fabsf(v.y)), fmaxf(fabsf(v.z), fabsf(v.w))));
    }
#pragma unroll
    for (int off = 1; off < 64; off <<= 1)
        a = fmaxf(a, __shfl_xor(a, off, 64));
    __shared__ float wred[4];
    if ((t & 63) == 0) wred[t >> 6] = a;
    __syncthreads();
    a = fmaxf(fmaxf(wred[0], wred[1]), fmaxf(wred[2], wred[3]));
    const float s = fmaxf(a / QMAXF, 1e-12f);
    if (t == 0) ws[nb * KB + kb] = s;

#pragma unroll
    for (int ii = 0; ii < 16; ++ii) {
        const int e = ii * 1024 + t * 4;
        const int row = e >> 7, col = e & 127;
        float4 v = vals[ii];
        char4 pk;
        pk.x = (char)(int)fminf(fmaxf(rintf(v.x / s), -128.f), 127.f);
        pk.y = (char)(int)fminf(fmaxf(rintf(v.y / s), -128.f), 127.f);
        pk.z = (char)(int)fminf(fmaxf(rintf(v.z / s), -128.f), 127.f);
        pk.w = (char)(int)fminf(fmaxf(rintf(v.w / s), -128.f), 127.f);
        *(char4*)(wq + (size_t)(n0 + row) * K_DIM + k0 + col) = pk;
    }
}

// ---------------- int8 GEMM with grouped dequant + bias ----------------
// 128x128 output tile / block; 4 waves, each 64x64 as 4x4 of 16x16x64 MFMA.
// K loop steps one 128-quant-block at a time; int32 accumulate within the
// block, fp32 dequant-accumulate across blocks.
__global__ __launch_bounds__(256, 2) void gemm_kernel(
    const int8_t* __restrict__ xq, const int8_t* __restrict__ wq,
    const float* __restrict__ xs_t, const float* __restrict__ ws,
    const float* __restrict__ bias, float* __restrict__ out, int M)
{
    __shared__ __align__(16) int8_t As[128 * 128];
    __shared__ __align__(16) int8_t Bs[128 * 128];
    __shared__ __align__(16) float  xs_s[KB * 128];   // [kb][row]
    __shared__ float ws_s[KB];

    const int t    = threadIdx.x;
    const int lane = t & 63;
    const int wave = t >> 6;
    const int nb   = blockIdx.x;
    const int n0   = nb * 128;
    const int m0   = blockIdx.y * 128;

    // stage all activation scales for this row-block: [kb][128 rows]
#pragma unroll
    for (int i = 0; i < 4; ++i) {
        const int idx = t * 4 + i * 1024;
        const int kbi = idx >> 7, r = idx & 127;
        *(float4*)&xs_s[idx] = *(const float4*)&xs_t[(size_t)kbi * M + m0 + r];
    }
    if (t < KB) ws_s[t] = ws[nb * KB + t];

    const int wm    = (wave >> 1) * 64;
    const int wn    = (wave & 1) * 64;
    const int frow  = lane & 15;          // row (A) / col (B) within 16-tile
    const int kq    = (lane >> 4) * 16;   // 16-byte k chunk within K=64
    const int quad4 = (lane >> 4) * 4;    // C/D row base within 16-tile

    float4 facc[4][4] = {};

    float bj[4];
#pragma unroll
    for (int j = 0; j < 4; ++j) bj[j] = bias[n0 + wn + j * 16 + frow];

    for (int kb = 0; kb < KB; ++kb) {
        __syncthreads();
        const int8_t* Ag = xq + (size_t)m0 * K_DIM + kb * 128;
        const int8_t* Bg = wq + (size_t)n0 * K_DIM + kb * 128;
#pragma unroll
        for (int it = 0; it < 4; ++it) {
            const int ci  = it * 256 + t;          // chunk id: row = ci>>3, ch = ci&7
            const int row = ci >> 3, ch = ci & 7;
            void* la = (void*)&As[(it * 256 + wave * 64) * 16];  // wave-uniform base
            void* lb = (void*)&Bs[(it * 256 + wave * 64) * 16];
            async_copy16(la, Ag + (size_t)row * K_DIM + ch * 16);
            async_copy16(lb, Bg + (size_t)row * K_DIM + ch * 16);
        }
        __syncthreads();

        v4i a0[4], a1[4], b0[4], b1[4];
#pragma unroll
        for (int i = 0; i < 4; ++i) {
            a0[i] = *(const v4i*)&As[(wm + i * 16 + frow) * 128 + kq];
            a1[i] = *(const v4i*)&As[(wm + i * 16 + frow) * 128 + 64 + kq];
            b0[i] = *(const v4i*)&Bs[(wn + i * 16 + frow) * 128 + kq];
            b1[i] = *(const v4i*)&Bs[(wn + i * 16 + frow) * 128 + 64 + kq];
        }
        const float wskb = ws_s[kb];
#pragma unroll
        for (int i = 0; i < 4; ++i) {
            float4 xs4 = *(const float4*)&xs_s[kb * 128 + wm + i * 16 + quad4];
            const float s0 = xs4.x * wskb, s1 = xs4.y * wskb;
            const float s2 = xs4.z * wskb, s3 = xs4.w * wskb;
#pragma unroll
            for (int j = 0; j < 4; ++j) {
                v4i d = __builtin_amdgcn_mfma_i32_16x16x64_i8(a0[i], b0[j], (v4i){0, 0, 0, 0}, 0, 0, 0);
                d = __builtin_amdgcn_mfma_i32_16x16x64_i8(a1[i], b1[j], d, 0, 0, 0);
                facc[i][j].x += (float)d[0] * s0;
                facc[i][j].y += (float)d[1] * s1;
                facc[i][j].z += (float)d[2] * s2;
                facc[i][j].w += (float)d[3] * s3;
            }
        }
    }

    // epilogue: C/D layout col = lane&15, row = (lane>>4)*4 + reg
#pragma unroll
    for (int i = 0; i < 4; ++i) {
#pragma unroll
        for (int r = 0; r < 4; ++r) {
            const int row = m0 + wm + i * 16 + quad4 + r;
            float* orow = out + (size_t)row * N_DIM + n0 + wn + frow;
#pragma unroll
            for (int j = 0; j < 4; ++j)
                orow[j * 16] = ((const float*)&facc[i][j])[r] + bj[j];
        }
    }
}

extern "C" void kernel_launch(void* const* d_in, const int* in_sizes, int n_in,
                              void* d_out, int out_size, void* d_ws, size_t ws_size,
                              hipStream_t stream)
{
    const float* x    = (const float*)d_in[0];
    const float* w    = (const float*)d_in[1];
    const float* bias = (const float*)d_in[2];
    float* out = (float*)d_out;
    const int M = in_sizes[0] / K_DIM;   // 8192

    // workspace layout
    int8_t* xq  = (int8_t*)d_ws;                                 // M*K
    int8_t* wqp = xq + (size_t)M * K_DIM;                        // N*K
    float*  xst = (float*)(wqp + (size_t)N_DIM * K_DIM);         // KB*M  [kb][M]
    float*  wsp = xst + (size_t)KB * M;                          // (N/128)*KB

    act_quant_kernel<<<M, 256, 0, stream>>>(x, xq, xst, M);
    weight_quant_kernel<<<(N_DIM / 128) * KB, 256, 0, stream>>>(w, wqp, wsp);
    gemm_kernel<<<dim3(N_DIM / 128, M / 128), 256, 0, stream>>>(
        xq, wqp, xst, wsp, bias, out, M);
}

// Round 2
// 446.105 us; speedup vs baseline: 1.0874x; 1.0874x over previous
//
#include <hip/hip_runtime.h>
#include <stdint.h>

#define K_DIM 4096
#define N_DIM 4096
#define KB    32          // K / 128
#define QMAXF 127.0f

typedef int v4i __attribute__((ext_vector_type(4)));

__device__ __forceinline__ void async_copy16(void* lds, const void* gptr) {
    __builtin_amdgcn_global_load_lds(
        (__attribute__((address_space(1))) void*)gptr,
        (__attribute__((address_space(3))) void*)lds, 16, 0, 0);
}

// ---------------- activation quant: per (row, 128-block) ----------------
__global__ __launch_bounds__(256) void act_quant_kernel(
    const float* __restrict__ x, int8_t* __restrict__ xq,
    float* __restrict__ xs_t, int M)
{
    const int m = blockIdx.x;
    const int t = threadIdx.x;
    const float* xrow = x + (size_t)m * K_DIM;
    int8_t* qrow = xq + (size_t)m * K_DIM;

#pragma unroll
    for (int p = 0; p < 4; ++p) {
        const int base = p * 1024 + t * 4;
        float4 v = *(const float4*)(xrow + base);
        float a = fmaxf(fmaxf(fabsf(v.x), fabsf(v.y)), fmaxf(fabsf(v.z), fabsf(v.w)));
#pragma unroll
        for (int off = 1; off < 32; off <<= 1)
            a = fmaxf(a, __shfl_xor(a, off, 64));
        const float s = fmaxf(a / QMAXF, 1e-12f);
        const float inv = 1.0f / s;      // one div per group (amortized 128x)
        float q0 = fminf(fmaxf(rintf(v.x * inv), -128.f), 127.f);
        float q1 = fminf(fmaxf(rintf(v.y * inv), -128.f), 127.f);
        float q2 = fminf(fmaxf(rintf(v.z * inv), -128.f), 127.f);
        float q3 = fminf(fmaxf(rintf(v.w * inv), -128.f), 127.f);
        char4 pk;
        pk.x = (char)(int)q0; pk.y = (char)(int)q1;
        pk.z = (char)(int)q2; pk.w = (char)(int)q3;
        *(char4*)(qrow + base) = pk;
        if ((t & 31) == 0) {
            const int g = base >> 7;
            xs_t[(size_t)g * M + m] = s;             // transposed [kb][M]
        }
    }
}

// ---------------- weight quant: per 128x128 block ----------------
__global__ __launch_bounds__(256) void weight_quant_kernel(
    const float* __restrict__ w, int8_t* __restrict__ wq, float* __restrict__ ws)
{
    const int nb = blockIdx.x >> 5;
    const int kb = blockIdx.x & 31;
    const int t  = threadIdx.x;
    const int n0 = nb * 128, k0 = kb * 128;

    float4 vals[16];
    float a = 0.f;
#pragma unroll
    for (int ii = 0; ii < 16; ++ii) {
        const int e = ii * 1024 + t * 4;
        const int row = e >> 7, col = e & 127;
        float4 v = *(const float4*)(w + (size_t)(n0 + row) * K_DIM + k0 + col);
        vals[ii] = v;
        a = fmaxf(a, fmaxf(fmaxf(fabsf(v.x), fabsf(v.y)), fmaxf(fabsf(v.z), fabsf(v.w))));
    }
#pragma unroll
    for (int off = 1; off < 64; off <<= 1)
        a = fmaxf(a, __shfl_xor(a, off, 64));
    __shared__ float wred[4];
    if ((t & 63) == 0) wred[t >> 6] = a;
    __syncthreads();
    a = fmaxf(fmaxf(wred[0], wred[1]), fmaxf(wred[2], wred[3]));
    const float s = fmaxf(a / QMAXF, 1e-12f);
    const float inv = 1.0f / s;
    if (t == 0) ws[nb * KB + kb] = s;

#pragma unroll
    for (int ii = 0; ii < 16; ++ii) {
        const int e = ii * 1024 + t * 4;
        const int row = e >> 7, col = e & 127;
        float4 v = vals[ii];
        char4 pk;
        pk.x = (char)(int)fminf(fmaxf(rintf(v.x * inv), -128.f), 127.f);
        pk.y = (char)(int)fminf(fmaxf(rintf(v.y * inv), -128.f), 127.f);
        pk.z = (char)(int)fminf(fmaxf(rintf(v.z * inv), -128.f), 127.f);
        pk.w = (char)(int)fminf(fmaxf(rintf(v.w * inv), -128.f), 127.f);
        *(char4*)(wq + (size_t)(n0 + row) * K_DIM + k0 + col) = pk;
    }
}

// ---------------- int8 GEMM with grouped dequant + bias ----------------
// 128x128 tile; 4 waves x (4x4 of 16x16x64 i8 MFMA); XOR-swizzled LDS:
// global chunk (row, c) lives at LDS slot row*8 + (c ^ (row&7)) so
// fragment ds_read_b128 hits all 32 banks across 8 rows (conflict-free).
__global__ __launch_bounds__(256, 3) void gemm_kernel(
    const int8_t* __restrict__ xq, const int8_t* __restrict__ wq,
    const float* __restrict__ xs_t, const float* __restrict__ ws,
    const float* __restrict__ bias, float* __restrict__ out, int M)
{
    __shared__ __align__(16) int8_t As[128 * 128];
    __shared__ __align__(16) int8_t Bs[128 * 128];
    __shared__ __align__(16) float  xs_s[KB * 128];   // [kb][row]
    __shared__ float ws_s[KB];

    const int t    = threadIdx.x;
    const int lane = t & 63;
    const int wave = t >> 6;
    const int nb   = blockIdx.x;
    const int n0   = nb * 128;
    const int m0   = blockIdx.y * 128;

#pragma unroll
    for (int i = 0; i < 4; ++i) {
        const int idx = t * 4 + i * 1024;
        const int kbi = idx >> 7, r = idx & 127;
        *(float4*)&xs_s[idx] = *(const float4*)&xs_t[(size_t)kbi * M + m0 + r];
    }
    if (t < KB) ws_s[t] = ws[nb * KB + t];

    const int wm    = (wave >> 1) * 64;
    const int wn    = (wave & 1) * 64;
    const int frow  = lane & 15;
    const int q     = lane >> 4;            // k-chunk index (0..3)
    const int quad4 = q * 4;                // C/D row base within 16-tile
    const int sw0   = ((q ^ (frow & 7)) * 16);   // swizzled byte offset, chunks 0..3
    // second half (chunk q+4): (q+4)^(frow&7) = (q^(frow&7))^4 -> sw0 ^ 64

    // per-lane source chunk for staging: LDS slot t gets global chunk
    // (row = ci>>3, c = (ci&7) ^ (row&7))
    float4 facc[4][4] = {};

    float bj[4];
#pragma unroll
    for (int j = 0; j < 4; ++j) bj[j] = bias[n0 + wn + j * 16 + frow];

    for (int kb = 0; kb < KB; ++kb) {
        __syncthreads();
        const int8_t* Ag = xq + (size_t)m0 * K_DIM + kb * 128;
        const int8_t* Bg = wq + (size_t)n0 * K_DIM + kb * 128;
#pragma unroll
        for (int it = 0; it < 4; ++it) {
            const int ci  = it * 256 + t;
            const int row = ci >> 3;
            const int c   = (ci & 7) ^ (row & 7);      // swizzled source chunk
            void* la = (void*)&As[(it * 256 + wave * 64) * 16];  // wave-uniform base
            void* lb = (void*)&Bs[(it * 256 + wave * 64) * 16];
            async_copy16(la, Ag + (size_t)row * K_DIM + c * 16);
            async_copy16(lb, Bg + (size_t)row * K_DIM + c * 16);
        }
        __syncthreads();

        v4i a0[4], a1[4], b0[4], b1[4];
#pragma unroll
        for (int i = 0; i < 4; ++i) {
            a0[i] = *(const v4i*)&As[(wm + i * 16 + frow) * 128 + sw0];
            a1[i] = *(const v4i*)&As[(wm + i * 16 + frow) * 128 + (sw0 ^ 64)];
            b0[i] = *(const v4i*)&Bs[(wn + i * 16 + frow) * 128 + sw0];
            b1[i] = *(const v4i*)&Bs[(wn + i * 16 + frow) * 128 + (sw0 ^ 64)];
        }
        const float wskb = ws_s[kb];
#pragma unroll
        for (int i = 0; i < 4; ++i) {
            float4 xs4 = *(const float4*)&xs_s[kb * 128 + wm + i * 16 + quad4];
            const float s0 = xs4.x * wskb, s1 = xs4.y * wskb;
            const float s2 = xs4.z * wskb, s3 = xs4.w * wskb;
#pragma unroll
            for (int j = 0; j < 4; ++j) {
                v4i d = __builtin_amdgcn_mfma_i32_16x16x64_i8(a0[i], b0[j], (v4i){0, 0, 0, 0}, 0, 0, 0);
                d = __builtin_amdgcn_mfma_i32_16x16x64_i8(a1[i], b1[j], d, 0, 0, 0);
                facc[i][j].x += (float)d[0] * s0;
                facc[i][j].y += (float)d[1] * s1;
                facc[i][j].z += (float)d[2] * s2;
                facc[i][j].w += (float)d[3] * s3;
            }
        }
    }

    // epilogue: C/D layout col = lane&15, row = (lane>>4)*4 + reg
#pragma unroll
    for (int i = 0; i < 4; ++i) {
#pragma unroll
        for (int r = 0; r < 4; ++r) {
            const int row = m0 + wm + i * 16 + quad4 + r;
            float* orow = out + (size_t)row * N_DIM + n0 + wn + frow;
#pragma unroll
            for (int j = 0; j < 4; ++j)
                orow[j * 16] = ((const float*)&facc[i][j])[r] + bj[j];
        }
    }
}

extern "C" void kernel_launch(void* const* d_in, const int* in_sizes, int n_in,
                              void* d_out, int out_size, void* d_ws, size_t ws_size,
                              hipStream_t stream)
{
    const float* x    = (const float*)d_in[0];
    const float* w    = (const float*)d_in[1];
    const float* bias = (const float*)d_in[2];
    float* out = (float*)d_out;
    const int M = in_sizes[0] / K_DIM;   // 8192

    int8_t* xq  = (int8_t*)d_ws;                                 // M*K
    int8_t* wqp = xq + (size_t)M * K_DIM;                        // N*K
    float*  xst = (float*)(wqp + (size_t)N_DIM * K_DIM);         // KB*M  [kb][M]
    float*  wsp = xst + (size_t)KB * M;                          // (N/128)*KB

    act_quant_kernel<<<M, 256, 0, stream>>>(x, xq, xst, M);
    weight_quant_kernel<<<(N_DIM / 128) * KB, 256, 0, stream>>>(w, wqp, wsp);
    gemm_kernel<<<dim3(N_DIM / 128, M / 128), 256, 0, stream>>>(
        xq, wqp, xst, wsp, bias, out, M);
}